// Round 2
// baseline (640.488 us; speedup 1.0000x reference)
//
#include <hip/hip_runtime.h>
#include <stdint.h>

typedef __attribute__((ext_vector_type(8))) short s16x8;
typedef __attribute__((ext_vector_type(4))) float f32x4;

__device__ __forceinline__ unsigned short f2bf(float f) {
  unsigned int u = __float_as_uint(f);
  u += 0x7fffu + ((u >> 16) & 1u);
  return (unsigned short)(u >> 16);
}
__device__ __forceinline__ float bf2f(unsigned short h) {
  return __uint_as_float(((unsigned int)h) << 16);
}
__device__ __forceinline__ f32x4 mfma16(s16x8 a, s16x8 b, f32x4 c) {
  return __builtin_amdgcn_mfma_f32_16x16x32_bf16(a, b, c, 0, 0, 0);
}

// ---------------- attention kernel: one block per batch ----------------
// LDS (union), stride 72 shorts (144B) everywhere:
//  K phases (4x 64-col chunks): Kh[64][72] @0 (9216B), Kl[64][72] @9216  -> 18432B
//  V phases (2x 128-row chunks): Vt[128][72] @0 (18432B), P[64][72] @18432 -> 27648B
#define STR 72

__global__ __launch_bounds__(256) void attn_kernel(
    const float* __restrict__ Vg, const float* __restrict__ Kg,
    const float* __restrict__ Qg, float* __restrict__ attn_out,
    unsigned short* __restrict__ xb /* bf16 x = attn+q, may be null */) {
  __shared__ __align__(16) char smem[27648];
  unsigned short* KhL = (unsigned short*)smem;
  unsigned short* KlL = (unsigned short*)(smem + 9216);
  unsigned short* VtL = (unsigned short*)smem;
  unsigned short* PL  = (unsigned short*)(smem + 18432);

  const int b = blockIdx.x;
  const int tid = threadIdx.x;
  const int lane = tid & 63;
  const int w = tid >> 6;  // wave id: owns S/A rows 16w..16w+15
  const int n = lane & 15;
  const int q = lane >> 4;

  const float* Qb = Qg + (size_t)b * 64 * 256;
  const float* Kb = Kg + (size_t)b * 64 * 256;
  const float* Vb = Vg + (size_t)b * 64 * 256;

  f32x4 accS[4];
#pragma unroll
  for (int c = 0; c < 4; ++c) accS[c] = f32x4{0.f, 0.f, 0.f, 0.f};

  // ---- S = Q K^T, hi/lo bf16 split, four 64-wide e-chunks ----
  for (int ph = 0; ph < 4; ++ph) {
    const int e0 = ph * 64;
    // stage K chunk 64x64 fp32 -> hi/lo bf16 LDS (coalesced float4)
#pragma unroll
    for (int it = 0; it < 4; ++it) {
      int i = it * 256 + tid;
      int row = i >> 4;
      int c4 = i & 15;
      float4 v = *(const float4*)(Kb + row * 256 + e0 + c4 * 4);
      ushort4 hi, lo;
      hi.x = f2bf(v.x); lo.x = f2bf(v.x - bf2f(hi.x));
      hi.y = f2bf(v.y); lo.y = f2bf(v.y - bf2f(hi.y));
      hi.z = f2bf(v.z); lo.z = f2bf(v.z - bf2f(hi.z));
      hi.w = f2bf(v.w); lo.w = f2bf(v.w - bf2f(hi.w));
      *(ushort4*)(KhL + row * STR + c4 * 4) = hi;
      *(ushort4*)(KlL + row * STR + c4 * 4) = lo;
    }
    __syncthreads();
#pragma unroll
    for (int kk = 0; kk < 2; ++kk) {
      const float* qsrc = Qb + (16 * w + n) * 256 + e0 + kk * 32 + q * 8;
      float4 a0 = *(const float4*)qsrc;
      float4 a1 = *(const float4*)(qsrc + 4);
      float av[8] = {a0.x, a0.y, a0.z, a0.w, a1.x, a1.y, a1.z, a1.w};
      s16x8 qh, ql;
#pragma unroll
      for (int j = 0; j < 8; ++j) {
        unsigned short h = f2bf(av[j]);
        qh[j] = (short)h;
        ql[j] = (short)f2bf(av[j] - bf2f(h));
      }
      const int colb = kk * 32 + q * 8;
#pragma unroll
      for (int c = 0; c < 4; ++c) {
        s16x8 kh = *(const s16x8*)(KhL + (16 * c + n) * STR + colb);
        s16x8 kl = *(const s16x8*)(KlL + (16 * c + n) * STR + colb);
        accS[c] = mfma16(qh, kh, accS[c]);
        accS[c] = mfma16(qh, kl, accS[c]);
        accS[c] = mfma16(ql, kh, accS[c]);
      }
    }
    __syncthreads();  // before restaging next chunk / Vt overwrite
  }

  // ---- in-register softmax. lane holds S[16w+4q+r][16c+n] in accS[c][r] ----
  const float scale = 0.125f;
  float p[4][4];
#pragma unroll
  for (int r = 0; r < 4; ++r) {
    float m = -1e30f;
#pragma unroll
    for (int c = 0; c < 4; ++c) m = fmaxf(m, accS[c][r]);
#pragma unroll
    for (int mk = 1; mk < 16; mk <<= 1) m = fmaxf(m, __shfl_xor(m, mk, 64));
    float s = 0.f;
#pragma unroll
    for (int c = 0; c < 4; ++c) {
      float e = __expf((accS[c][r] - m) * scale);
      p[c][r] = e;
      s += e;
    }
#pragma unroll
    for (int mk = 1; mk < 16; mk <<= 1) s += __shfl_xor(s, mk, 64);
    float inv = 1.0f / s;
#pragma unroll
    for (int c = 0; c < 4; ++c) p[c][r] *= inv;
  }

  // ---- A = P V in two 128-col passes; P staged once ----
  const int vr = tid & 127;   // e-row within chunk
  const int vh = tid >> 7;    // t-half
  for (int ps = 0; ps < 2; ++ps) {
    if (ps) __syncthreads();  // pass-0 MFMA reads done before Vt overwrite
    // stage V^T chunk: Vt[e][t], e in [128ps,128ps+128), b128 writes
#pragma unroll
    for (int pk = 0; pk < 4; ++pk) {
      int t0 = vh * 32 + pk * 8;
      s16x8 pkd;
#pragma unroll
      for (int j = 0; j < 8; ++j)
        pkd[j] = (short)f2bf(Vb[(t0 + j) * 256 + ps * 128 + vr]);
      *(s16x8*)(VtL + vr * STR + t0) = pkd;
    }
    if (ps == 0) {
#pragma unroll
      for (int r = 0; r < 4; ++r) {
        int row = 16 * w + 4 * q + r;
#pragma unroll
        for (int c = 0; c < 4; ++c) PL[row * STR + 16 * c + n] = f2bf(p[c][r]);
      }
    }
    __syncthreads();

    f32x4 accA[8];
#pragma unroll
    for (int c = 0; c < 8; ++c) accA[c] = f32x4{0.f, 0.f, 0.f, 0.f};
#pragma unroll
    for (int ks = 0; ks < 2; ++ks) {
      const int colb = ks * 32 + q * 8;
      s16x8 af = *(const s16x8*)(PL + (16 * w + n) * STR + colb);
#pragma unroll
      for (int c = 0; c < 8; ++c) {
        s16x8 bf = *(const s16x8*)(VtL + (16 * c + n) * STR + colb);
        accA[c] = mfma16(af, bf, accA[c]);
      }
    }
    // epilogue for this col-chunk
#pragma unroll
    for (int r = 0; r < 4; ++r) {
      int t = 16 * w + 4 * q + r;
      size_t base = ((size_t)b * 64 + t) * 256;
#pragma unroll
      for (int c = 0; c < 8; ++c) {
        int e = ps * 128 + 16 * c + n;
        float aval = accA[c][r];
        attn_out[base + e] = aval;
        if (xb) xb[base + e] = f2bf(aval + Qb[t * 256 + e]);
      }
    }
  }
}

// ---------------- W_ff fp32 -> bf16 ----------------
__global__ __launch_bounds__(256) void w2b_kernel(const float* __restrict__ W,
                                                  unsigned short* __restrict__ Wb) {
  int i = blockIdx.x * 256 + threadIdx.x;
  float4 v = ((const float4*)W)[i];
  ushort4 o;
  o.x = f2bf(v.x); o.y = f2bf(v.y); o.z = f2bf(v.z); o.w = f2bf(v.w);
  ((ushort4*)Wb)[i] = o;
}

// ---------------- out = bias (init before ff atomics) ----------------
__global__ __launch_bounds__(256) void bias_init_kernel(const float* __restrict__ bias,
                                                        float* __restrict__ out) {
  int idx = blockIdx.x * 256 + threadIdx.x;
  out[idx] = bias[idx & 255];
}

// ---------------- FF GEMM: out += x @ W^T (atomic), 64x64 tiles, KS=8 ----------------
template <bool USE_XB>
__global__ __launch_bounds__(256) void ff_kernel(
    const unsigned short* __restrict__ xb, const float* __restrict__ attn,
    const float* __restrict__ query, const unsigned short* __restrict__ Wb,
    float* __restrict__ out, int kchunk) {
  __shared__ __align__(16) unsigned short As[64 * STR];
  __shared__ __align__(16) unsigned short Bs[64 * STR];
  const int tid = threadIdx.x;
  const int lane = tid & 63, w = tid >> 6, n = lane & 15, q = lane >> 4;
  const int m0 = blockIdx.x * 64;
  const int n0 = blockIdx.y * 64;
  const int k0 = blockIdx.z * kchunk;

  f32x4 acc[4];
#pragma unroll
  for (int c = 0; c < 4; ++c) acc[c] = f32x4{0.f, 0.f, 0.f, 0.f};

  const int srow = tid >> 3;       // 0..31
  const int scol = (tid & 7) * 8;  // 0..56

  uint4 areg[2], breg[2];
  float4 fa[2][2], fq[2][2];

  auto load_regs = [&](int kk) {
#pragma unroll
    for (int rr = 0; rr < 2; ++rr) {
      int row = rr * 32 + srow;
      size_t ga = (size_t)(m0 + row) * 16384 + k0 + kk + scol;
      if (USE_XB) {
        areg[rr] = *(const uint4*)(xb + ga);
      } else {
        fa[rr][0] = *(const float4*)(attn + ga);
        fa[rr][1] = *(const float4*)(attn + ga + 4);
        fq[rr][0] = *(const float4*)(query + ga);
        fq[rr][1] = *(const float4*)(query + ga + 4);
      }
      size_t gw = (size_t)(n0 + row) * 16384 + k0 + kk + scol;
      breg[rr] = *(const uint4*)(Wb + gw);
    }
  };

  const int niter = kchunk / 64;
  load_regs(0);
  for (int i = 0; i < niter; ++i) {
    if (i) __syncthreads();  // prior MFMA reads done before overwrite
#pragma unroll
    for (int rr = 0; rr < 2; ++rr) {
      int row = rr * 32 + srow;
      if (USE_XB) {
        *(uint4*)(As + row * STR + scol) = areg[rr];
      } else {
        ushort4 h0, h1;
        h0.x = f2bf(fa[rr][0].x + fq[rr][0].x); h0.y = f2bf(fa[rr][0].y + fq[rr][0].y);
        h0.z = f2bf(fa[rr][0].z + fq[rr][0].z); h0.w = f2bf(fa[rr][0].w + fq[rr][0].w);
        h1.x = f2bf(fa[rr][1].x + fq[rr][1].x); h1.y = f2bf(fa[rr][1].y + fq[rr][1].y);
        h1.z = f2bf(fa[rr][1].z + fq[rr][1].z); h1.w = f2bf(fa[rr][1].w + fq[rr][1].w);
        *(ushort4*)(As + row * STR + scol) = h0;
        *(ushort4*)(As + row * STR + scol + 4) = h1;
      }
      *(uint4*)(Bs + row * STR + scol) = breg[rr];
    }
    if (i + 1 < niter) load_regs((i + 1) * 64);  // overlaps MFMA phase
    __syncthreads();
#pragma unroll
    for (int ks = 0; ks < 2; ++ks) {
      const int colb = ks * 32 + q * 8;
      s16x8 af = *(const s16x8*)(As + (16 * w + n) * STR + colb);
#pragma unroll
      for (int c = 0; c < 4; ++c) {
        s16x8 bf = *(const s16x8*)(Bs + (16 * c + n) * STR + colb);
        acc[c] = mfma16(af, bf, acc[c]);
      }
    }
  }
#pragma unroll
  for (int r = 0; r < 4; ++r) {
    int m = m0 + 16 * w + 4 * q + r;
#pragma unroll
    for (int c = 0; c < 4; ++c) {
      int nn = n0 + 16 * c + n;
      atomicAdd(out + (size_t)m * 256 + nn, acc[c][r]);
    }
  }
}

// ---------------- final in-place ReLU ----------------
__global__ __launch_bounds__(256) void relu_kernel(float* __restrict__ out) {
  int idx = blockIdx.x * 256 + threadIdx.x;
  out[idx] = fmaxf(out[idx], 0.f);
}

extern "C" void kernel_launch(void* const* d_in, const int* in_sizes, int n_in,
                              void* d_out, int out_size, void* d_ws, size_t ws_size,
                              hipStream_t stream) {
  const float* value = (const float*)d_in[0];
  const float* key   = (const float*)d_in[1];
  const float* query = (const float*)d_in[2];
  const float* W_ff  = (const float*)d_in[4];
  const float* b_ff  = (const float*)d_in[5];

  float* out  = (float*)d_out;
  float* attn = out + (size_t)2048 * 256;  // outputs: (out, attention) concatenated

  const size_t wb_bytes = (size_t)256 * 16384 * 2;       // 8 MB bf16 W
  const size_t xb_bytes = (size_t)2048 * 64 * 256 * 2;   // 64 MB bf16 x
  unsigned short* Wb = (unsigned short*)d_ws;
  bool use_xb = ws_size >= wb_bytes + xb_bytes;
  unsigned short* xb = use_xb ? (unsigned short*)((char*)d_ws + wb_bytes) : nullptr;

  const int KS = 8;
  const int kchunk = 16384 / KS;

  w2b_kernel<<<4096, 256, 0, stream>>>(W_ff, Wb);
  bias_init_kernel<<<2048, 256, 0, stream>>>(b_ff, out);
  attn_kernel<<<2048, 256, 0, stream>>>(value, key, query, attn, xb);
  dim3 gb(32, 4, KS);
  if (use_xb)
    ff_kernel<true><<<gb, 256, 0, stream>>>(xb, nullptr, nullptr, Wb, out, kchunk);
  else
    ff_kernel<false><<<gb, 256, 0, stream>>>(nullptr, attn, query, Wb, out, kchunk);
  relu_kernel<<<2048, 256, 0, stream>>>(out);
}